// Round 2
// baseline (3975.924 us; speedup 1.0000x reference)
//
#include <hip/hip_runtime.h>
#include <stdint.h>

// Problem: B=256, D=16, T_IN=512, T_OUT=200, H=512.
// Persistent kernel: 16 groups x 16 WGs. Group = 16 batches; WG = 32 hidden units
// (128 gate rows). W_hh slice lives in VGPRs as bf16 MFMA fragments. Per step:
// stage group h (fp32 -> bf16 hi+lo) into swizzled LDS, MFMA gates, lane-local
// LSTM cell, write h slice to double-buffered global, group spin-barrier via
// agent-scope atomics -> correct across XCDs.

#define NGRP 16
#define NWG  16
#define GB   16     // batches per group
#define HS   32     // hidden units per WG
#define HH   512
#define DD   16
#define TIN  512
#define TOUT 200

typedef short     s16x8 __attribute__((ext_vector_type(8)));   // 8 bf16 (guide: frag_ab)
typedef float     f32x4 __attribute__((ext_vector_type(4)));
typedef uint32_t  u32x4 __attribute__((ext_vector_type(4)));

// workspace layout (bytes)
#define H32_OFF 0u            // 2 buffers x 256x512 f32 = 1 MiB
#define HBUF    131072u       // u32 elements per h buffer (256*512)
#define XN_OFF  1048576u      // normalized x, bf16 hi/lo packed: 16g*512t*16b*16 u32 = 8 MiB
#define ST_OFF  9437184u      // stats: 256 b x 16 d x {mean,std} f32 = 32 KiB
#define FL_OFF  9469952u      // flags: 16 groups x 128 B

#define AGENT __HIP_MEMORY_SCOPE_AGENT
#define RLX   __ATOMIC_RELAXED

__device__ __forceinline__ uint32_t aload(uint32_t* p){ return __hip_atomic_load(p, RLX, AGENT); }
__device__ __forceinline__ void astore(uint32_t* p, uint32_t v){ __hip_atomic_store(p, v, RLX, AGENT); }
__device__ __forceinline__ float u2f(uint32_t u){ return __builtin_bit_cast(float, u); }
__device__ __forceinline__ uint32_t f2u(float f){ return __builtin_bit_cast(uint32_t, f); }
__device__ __forceinline__ unsigned short bfu(float f){ __bf16 h=(__bf16)f; return __builtin_bit_cast(unsigned short, h); }
__device__ __forceinline__ float sigf(float x){ return 1.0f/(1.0f+__expf(-x)); }
__device__ __forceinline__ float tanhx(float x){ float e=__expf(2.0f*x); return 1.0f-2.0f/(e+1.0f); }
// 16B-slot XOR swizzle for 1024B-stride rows: rows 0..7 -> distinct 16B slots
__device__ __forceinline__ uint32_t swz(int row, int byt){ return (uint32_t)(row*1024 + (byt ^ ((row&7)<<4))); }

__device__ __forceinline__ f32x4 mfma(s16x8 a, s16x8 b, f32x4 c){
  return __builtin_amdgcn_mfma_f32_16x16x32_bf16(a, b, c, 0, 0, 0);
}
__device__ __forceinline__ s16x8 ld16(const uint8_t* p){
  return __builtin_bit_cast(s16x8, *(const u32x4*)p);
}

__global__ __launch_bounds__(256, 1) void lstm_k(
    const float* __restrict__ x,   const float* __restrict__ Wih, const float* __restrict__ Whh,
    const float* __restrict__ bih, const float* __restrict__ bhh,
    const float* __restrict__ Wpj, const float* __restrict__ bpj,
    const float* __restrict__ rw,  const float* __restrict__ rb,
    float* __restrict__ out, uint8_t* __restrict__ wsb)
{
  __shared__ __align__(16) uint8_t ldsHi[16*1024];   // staged h hi, [b][512] bf16, swizzled
  __shared__ __align__(16) uint8_t ldsLo[16*1024];   // staged h lo
  __shared__ __align__(16) uint8_t ldsWp[16*1024];   // W_proj [16][512] bf16, swizzled
  __shared__ __align__(16) uint8_t projb[16*64];     // proj [b][32 bf16]: d0..15 hi | d0..15 lo
  __shared__ float statM[16][16], statS[16][16];
  __shared__ float meanL[16], rstdL[16], rwL[16], rbL[16];
  __shared__ float sred[8][32][4];

  const int bid  = blockIdx.x;
  const int g    = (bid & 7) | ((bid >> 7) << 3);   // group 0..15 (same-XCD heuristic)
  const int w    = (bid >> 3) & 15;                 // wg-in-group 0..15
  const int tid  = threadIdx.x;
  const int lane = tid & 63;
  const int wv   = tid >> 6;                        // wave 0..3
  const int l15  = lane & 15;
  const int l4   = lane >> 4;

  uint32_t* h32 = (uint32_t*)(wsb + H32_OFF);
  uint32_t* xnw = (uint32_t*)(wsb + XN_OFF);
  uint32_t* stw = (uint32_t*)(wsb + ST_OFF);
  uint32_t* flg = (uint32_t*)(wsb + FL_OFF) + g*32;

  // ---------------- setup ----------------
  if (tid < 16) { rwL[tid] = rw[tid]; rbL[tid] = rb[tid]; }

  // W_hh slice -> registers (bf16 A-fragments). Gate-row order within WG: mloc -> grow.
  s16x8 Ahh[2][16];
  s16x8 Aih[2];
  #pragma unroll
  for (int f = 0; f < 2; ++f) {
    const int mloc = 32*wv + 16*f + l15;
    const int grow = (mloc & 3)*512 + HS*w + (mloc >> 2);
    const float* wr = Whh + (size_t)grow*512 + l4*8;
    #pragma unroll
    for (int kk = 0; kk < 16; ++kk) {
      f32x4 a  = *(const f32x4*)(wr + kk*32);
      f32x4 b2 = *(const f32x4*)(wr + kk*32 + 4);
      s16x8 v;
      v[0]=(short)bfu(a[0]);  v[1]=(short)bfu(a[1]);  v[2]=(short)bfu(a[2]);  v[3]=(short)bfu(a[3]);
      v[4]=(short)bfu(b2[0]); v[5]=(short)bfu(b2[1]); v[6]=(short)bfu(b2[2]); v[7]=(short)bfu(b2[3]);
      Ahh[f][kk] = v;
    }
    // W_ih slice: K=16 duplicated into k=16..31 (pairs with x hi|lo packing)
    const float* wi = Wih + (size_t)grow*16 + (l4 & 1)*8;
    f32x4 a  = *(const f32x4*)(wi);
    f32x4 b2 = *(const f32x4*)(wi + 4);
    s16x8 v;
    v[0]=(short)bfu(a[0]);  v[1]=(short)bfu(a[1]);  v[2]=(short)bfu(a[2]);  v[3]=(short)bfu(a[3]);
    v[4]=(short)bfu(b2[0]); v[5]=(short)bfu(b2[1]); v[6]=(short)bfu(b2[2]); v[7]=(short)bfu(b2[3]);
    Aih[f] = v;
  }
  // biases (C/D layout rows: m = l4*4 + r)
  float bias[2][4];
  #pragma unroll
  for (int f = 0; f < 2; ++f) {
    #pragma unroll
    for (int r = 0; r < 4; ++r) {
      const int mloc = 32*wv + 16*f + l4*4 + r;
      const int grow = (mloc & 3)*512 + HS*w + (mloc >> 2);
      bias[f][r] = bih[grow] + bhh[grow];
    }
  }
  float bpv[4];
  #pragma unroll
  for (int r = 0; r < 4; ++r) bpv[r] = bpj[l4*4 + r];

  // W_proj -> LDS bf16 swizzled
  #pragma unroll
  for (int j = 0; j < 8; ++j) {
    const int idx = (tid + 256*j)*4;
    const int row = idx >> 9, col = idx & 511;
    f32x4 a = *(const f32x4*)(Wpj + idx);
    uint2 hv;
    hv.x = (uint32_t)bfu(a[0]) | ((uint32_t)bfu(a[1]) << 16);
    hv.y = (uint32_t)bfu(a[2]) | ((uint32_t)bfu(a[3]) << 16);
    *(uint2*)(ldsWp + swz(row, col*2)) = hv;
  }

  // RevIN stats for this WG's batch (b = 16g + w)
  const int sp = tid & 7, sc = tid >> 3;
  const float* xb = x + (size_t)(GB*g + w)*DD*TIN;
  {
    float s1a=0, s2a=0, s1b=0, s2b=0;
    for (int j = 0; j < 16; ++j) {
      const int t = sc*16 + j;
      const float a  = xb[(2*sp)*TIN + t];
      const float b2 = xb[(2*sp+1)*TIN + t];
      s1a += a; s2a += a*a; s1b += b2; s2b += b2*b2;
    }
    sred[sp][sc][0]=s1a; sred[sp][sc][1]=s2a; sred[sp][sc][2]=s1b; sred[sp][sc][3]=s2b;
  }
  __syncthreads();
  if (tid < 16) {
    const int d = tid, p = d >> 1, o = (d & 1)*2;
    float s1 = 0, s2 = 0;
    for (int c2 = 0; c2 < 32; ++c2) { s1 += sred[p][c2][o]; s2 += sred[p][c2][o+1]; }
    const float mean = s1 * (1.0f/512.0f);
    float var = s2 * (1.0f/512.0f) - mean*mean;
    var = fmaxf(var, 0.0f);
    const float sd = sqrtf(var + 1e-5f);
    meanL[d] = mean; rstdL[d] = 1.0f/sd;
    const int bb = GB*g + w;
    astore(stw + (bb*16 + d)*2 + 0, f2u(mean));
    astore(stw + (bb*16 + d)*2 + 1, f2u(sd));
  }
  __syncthreads();
  // normalized x -> workspace as bf16 hi|lo packed (B-fragment-ready layout)
  {
    const float m0 = meanL[2*sp],   r0 = rstdL[2*sp]*rwL[2*sp],     q0 = rbL[2*sp];
    const float m1 = meanL[2*sp+1], r1 = rstdL[2*sp+1]*rwL[2*sp+1], q1 = rbL[2*sp+1];
    for (int j = 0; j < 16; ++j) {
      const int t = sc*16 + j;
      const float a  = xb[(2*sp)*TIN + t];
      const float b2 = xb[(2*sp+1)*TIN + t];
      const float x0 = (a - m0)*r0 + q0;
      const float x1 = (b2 - m1)*r1 + q1;
      const __bf16 h0 = (__bf16)x0, h1 = (__bf16)x1;
      const uint32_t hv = (uint32_t)__builtin_bit_cast(unsigned short, h0)
                        | ((uint32_t)__builtin_bit_cast(unsigned short, h1) << 16);
      const uint32_t lv = (uint32_t)bfu(x0 - (float)h0) | ((uint32_t)bfu(x1 - (float)h1) << 16);
      const uint32_t base = ((uint32_t)(g*512 + t)*16 + w)*16;
      astore(xnw + base + sp,     hv);
      astore(xnw + base + 8 + sp, lv);
    }
  }
  // zero h buffer 0 (this WG's column slice, all 16 batches)
  {
    const int e = tid*2;
    const int b0 = e >> 5, k0 = HS*w + (e & 31);
    astore(h32 + (GB*g + b0)*HH + k0,     0u);
    astore(h32 + (GB*g + b0)*HH + k0 + 1, 0u);
  }
  __syncthreads();                       // drains all stores (compiler emits vmcnt(0))
  if (tid == 0) astore(flg + w, 1u);     // signal setup done

  // ---------------- recurrence ----------------
  float cst[2] = {0.0f, 0.0f};
  uint32_t gen = 1;
  uint32_t par = 0;                      // h double-buffer parity

  for (int t = 0; t < TIN + TOUT; ++t) {
    const bool dec = (t >= TIN);

    // prefetch encoder x-fragment (xn immutable after gen 1; safe pre-poll for t>0)
    u32x4 xv;
    uint32_t* xp = xnw + ((uint32_t)(g*512 + t)*16 + l15)*16 + l4*4;
    if (!dec && t > 0) { xv[0]=aload(xp); xv[1]=aload(xp+1); xv[2]=aload(xp+2); xv[3]=aload(xp+3); }

    // group barrier: wait until all 16 WGs reached generation `gen`
    if (wv == 0) {
      int guard = 0;
      for (;;) {
        const int v = (l15 == lane) ? (int)aload(flg + l15) : (int)gen;  // lanes 0..15 poll
        if (__all(v >= (int)gen)) break;
        if (++guard > (1 << 22)) break;  // safety valve, must never fire
        __builtin_amdgcn_s_sleep(2);
      }
    }
    __syncthreads();
    if (!dec && t == 0) {
      xv[0]=aload(xp); xv[1]=aload(xp+1); xv[2]=aload(xp+2); xv[3]=aload(xp+3);
      if (w == 0) {  // leader WG caches group stats for output denorm
        const int b0 = tid >> 4, d0 = tid & 15;
        statM[b0][d0] = u2f(aload(stw + ((GB*g + b0)*16 + d0)*2));
        statS[b0][d0] = u2f(aload(stw + ((GB*g + b0)*16 + d0)*2 + 1));
      }
    }

    // stage h (fp32 global, coherent) -> LDS bf16 hi + lo, swizzled
    {
      uint32_t* hb = h32 + par*HBUF + (uint32_t)(GB*g)*HH;
      #pragma unroll
      for (int j = 0; j < 8; ++j) {
        const int idx4 = (tid + 256*j)*4;
        const int b0 = idx4 >> 9, k0 = idx4 & 511;
        const float f0 = u2f(aload(hb + idx4));
        const float f1 = u2f(aload(hb + idx4 + 1));
        const float f2 = u2f(aload(hb + idx4 + 2));
        const float f3 = u2f(aload(hb + idx4 + 3));
        const __bf16 h0=(__bf16)f0, h1=(__bf16)f1, h2=(__bf16)f2, h3=(__bf16)f3;
        uint2 hv, lv;
        hv.x = (uint32_t)__builtin_bit_cast(unsigned short,h0) | ((uint32_t)__builtin_bit_cast(unsigned short,h1)<<16);
        hv.y = (uint32_t)__builtin_bit_cast(unsigned short,h2) | ((uint32_t)__builtin_bit_cast(unsigned short,h3)<<16);
        lv.x = (uint32_t)bfu(f0-(float)h0) | ((uint32_t)bfu(f1-(float)h1)<<16);
        lv.y = (uint32_t)bfu(f2-(float)h2) | ((uint32_t)bfu(f3-(float)h3)<<16);
        *(uint2*)(ldsHi + swz(b0, k0*2)) = hv;
        *(uint2*)(ldsLo + swz(b0, k0*2)) = lv;
      }
    }
    __syncthreads();

    // gates GEMM: acc = bias + x_part + W_hh*(h_hi + h_lo)
    f32x4 ah[2], al[2], pa, pl;
    #pragma unroll
    for (int f = 0; f < 2; ++f) {
      #pragma unroll
      for (int r = 0; r < 4; ++r) { ah[f][r] = bias[f][r]; al[f][r] = 0.0f; }
    }
    #pragma unroll
    for (int r = 0; r < 4; ++r) { pa[r] = bpv[r]; pl[r] = 0.0f; }

    if (!dec) {  // encoder x-part (k 0..15 = x hi, k 16..31 = x lo; Aih duplicated)
      const s16x8 bx = __builtin_bit_cast(s16x8, xv);
      ah[0] = mfma(Aih[0], bx, ah[0]);
      ah[1] = mfma(Aih[1], bx, ah[1]);
    }
    #pragma unroll
    for (int kk = 0; kk < 16; ++kk) {
      const int byt = kk*64 + l4*16;
      const s16x8 bh = ld16(ldsHi + swz(l15, byt));
      const s16x8 bl = ld16(ldsLo + swz(l15, byt));
      ah[0] = mfma(Ahh[0][kk], bh, ah[0]);
      al[0] = mfma(Ahh[0][kk], bl, al[0]);
      ah[1] = mfma(Ahh[1][kk], bh, ah[1]);
      al[1] = mfma(Ahh[1][kk], bl, al[1]);
      if (dec && wv == 0) {  // wave0 also computes proj = h @ W_proj^T
        const s16x8 wa = ld16(ldsWp + swz(l15, byt));
        pa = mfma(wa, bh, pa);
        pl = mfma(wa, bl, pl);
      }
    }

    if (dec) {
      if (wv == 0) {  // publish proj (hi|lo) to LDS; leader WG writes denormed output
        #pragma unroll
        for (int r = 0; r < 4; ++r) {
          const float pv = pa[r] + pl[r];
          const int d = l4*4 + r;
          const __bf16 ph = (__bf16)pv;
          *(unsigned short*)(projb + l15*64 + d*2)      = __builtin_bit_cast(unsigned short, ph);
          *(unsigned short*)(projb + l15*64 + 32 + d*2) = bfu(pv - (float)ph);
          if (w == 0) {
            const float yv = (pv - rbL[d]) / (rwL[d] + 1e-10f) * statS[l15][d] + statM[l15][d];
            out[(size_t)(GB*g + l15)*(DD*TOUT) + d*TOUT + (t - TIN)] = yv;
          }
        }
      }
      __syncthreads();
      const s16x8 bxp = ld16(projb + l15*64 + l4*16);  // decoder x-part = proj (hi|lo)
      ah[0] = mfma(Aih[0], bxp, ah[0]);
      ah[1] = mfma(Aih[1], bxp, ah[1]);
    }

    // LSTM cell (lane-local: regs r = {i,f,g,o} of one hidden unit) + h write
    {
      uint32_t* hn = h32 + (par ^ 1)*HBUF + (uint32_t)(GB*g)*HH;
      #pragma unroll
      for (int f = 0; f < 2; ++f) {
        const float gi = ah[f][0] + al[f][0];
        const float gf = ah[f][1] + al[f][1];
        const float gg = ah[f][2] + al[f][2];
        const float go = ah[f][3] + al[f][3];
        const float c2 = sigf(gf)*cst[f] + sigf(gi)*tanhx(gg);
        const float h2 = sigf(go)*tanhx(c2);
        cst[f] = c2;
        const int kidx = HS*w + 8*wv + 4*f + l4;
        astore(hn + (uint32_t)l15*HH + kidx, f2u(h2));
      }
    }
    __syncthreads();            // drains h stores before signaling
    ++gen;
    if (tid == 0) astore(flg + w, gen);
    par ^= 1;
  }
}

extern "C" void kernel_launch(void* const* d_in, const int* in_sizes, int n_in,
                              void* d_out, int out_size, void* d_ws, size_t ws_size,
                              hipStream_t stream) {
  (void)in_sizes; (void)n_in; (void)out_size; (void)ws_size;
  lstm_k<<<dim3(256), dim3(256), 0, stream>>>(
      (const float*)d_in[0], (const float*)d_in[1], (const float*)d_in[2],
      (const float*)d_in[3], (const float*)d_in[4], (const float*)d_in[5],
      (const float*)d_in[6], (const float*)d_in[7], (const float*)d_in[8],
      (float*)d_out, (uint8_t*)d_ws);
}